// Round 3
// baseline (1146.928 us; speedup 1.0000x reference)
//
#include <hip/hip_runtime.h>
#include <hip/hip_bf16.h>
#include <cstddef>

#define BATCH 8
#define SEQ   2048
#define DEMB  1024
#define DQ    512

typedef __attribute__((ext_vector_type(8))) short bf16x8;
typedef __attribute__((ext_vector_type(4))) float f32x4;
typedef __attribute__((ext_vector_type(4))) unsigned short u16x4;

static __device__ __forceinline__ unsigned short bft(float f) {
  union { float f; unsigned u; } v; v.f = f;
  return (unsigned short)(v.u >> 16);            // truncating fp32->bf16
}
static __device__ __forceinline__ float bf2f(unsigned short h) {
  union { float f; unsigned u; } v; v.u = ((unsigned)h) << 16;
  return v.f;
}

// ---------------------------------------------------------------------------
// Split the three weight matrices into (hi, lo) bf16 planes, TRANSPOSED to
// [n][k] layout so the GEMM B-fragment (8 consecutive k per lane) is a 16B load.
// ---------------------------------------------------------------------------
__global__ __launch_bounds__(256) void wsplit(
    const float* __restrict__ Wq, const float* __restrict__ Wk,
    const float* __restrict__ Wv,
    unsigned short* __restrict__ whi, unsigned short* __restrict__ wlo)
{
  int qidx = blockIdx.x * 256 + threadIdx.x;     // 0 .. 3*1024*128-1
  int w   = qidx >> 17;                          // / (1024*128)
  int rem = qidx & 131071;
  int k   = rem >> 7;                            // 0..1023
  int n   = (rem & 127) * 4;                     // 0..508
  const float* W = (w == 0) ? Wq : (w == 1) ? Wk : Wv;
  float4 v = *(const float4*)&W[(size_t)k * DQ + n];
  float vv[4] = {v.x, v.y, v.z, v.w};
  size_t base = (size_t)w * (DQ * DEMB);
  #pragma unroll
  for (int j = 0; j < 4; j++) {
    unsigned short h = bft(vv[j]);
    unsigned short lo = bft(vv[j] - bf2f(h));
    whi[base + (size_t)(n + j) * DEMB + k] = h;
    wlo[base + (size_t)(n + j) * DEMB + k] = lo;
  }
}

// ---------------------------------------------------------------------------
// Projection GEMM on MFMA, 2-term split, 3-pass (hi*hi + hi*lo + lo*hi).
// C[M=16384, N=512] = X[M,K=1024] * W[K,N].  BM=128, BN=128, BK=32,
// 256 threads = 4 waves of 64x64, 4x4 frags of 16x16x32.
// ---------------------------------------------------------------------------
__global__ __launch_bounds__(256) void proj_mfma(
    const float* __restrict__ x,
    const unsigned short* __restrict__ whi,
    const unsigned short* __restrict__ wlo,
    unsigned short* __restrict__ khi, unsigned short* __restrict__ klo,
    unsigned short* __restrict__ vt,
    unsigned short* __restrict__ qpack)
{
  const int w  = blockIdx.z;
  const int mt = blockIdx.y, nt = blockIdx.x;

  __shared__ unsigned short Xh[128][40], Xl[128][40];  // [m][k], pad 40
  __shared__ unsigned short Wh[128][40], Wl[128][40];  // [n][k], pad 40

  const int tid  = threadIdx.x;
  const int wave = tid >> 6, l = tid & 63;
  const int wm = wave >> 1, wn = wave & 1;
  const int lo4 = l & 15, hi2 = l >> 4;

  f32x4 acc[4][4];
  #pragma unroll
  for (int mf = 0; mf < 4; mf++)
    #pragma unroll
    for (int nf = 0; nf < 4; nf++)
      #pragma unroll
      for (int i = 0; i < 4; i++) acc[mf][nf][i] = 0.f;

  const int    srow  = tid >> 1;
  const int    skh   = (tid & 1) * 16;
  const size_t xbase = (size_t)(mt * 128 + srow) * DEMB + skh;
  const size_t wbase = (size_t)w * (DQ * DEMB) + (size_t)(nt * 128 + srow) * DEMB + skh;

  #pragma unroll 1
  for (int k0 = 0; k0 < DEMB; k0 += 32) {
    // ---- stage X tile (fp32 -> hi/lo bf16 in-register) ----
    float xs[16];
    #pragma unroll
    for (int i = 0; i < 4; i++) {
      float4 t = *(const float4*)&x[xbase + k0 + i * 4];
      xs[i*4+0] = t.x; xs[i*4+1] = t.y; xs[i*4+2] = t.z; xs[i*4+3] = t.w;
    }
    #pragma unroll
    for (int i = 0; i < 4; i++) {
      u16x4 hv, lv;
      #pragma unroll
      for (int j = 0; j < 4; j++) {
        unsigned short h = bft(xs[i*4+j]);
        hv[j] = h;
        lv[j] = bft(xs[i*4+j] - bf2f(h));
      }
      *(u16x4*)&Xh[srow][skh + i*4] = hv;
      *(u16x4*)&Xl[srow][skh + i*4] = lv;
    }
    // ---- stage W tile (pre-split bf16 planes, already [n][k]) ----
    {
      bf16x8 a0 = *(const bf16x8*)&whi[wbase + k0];
      bf16x8 a1 = *(const bf16x8*)&whi[wbase + k0 + 8];
      bf16x8 b0 = *(const bf16x8*)&wlo[wbase + k0];
      bf16x8 b1 = *(const bf16x8*)&wlo[wbase + k0 + 8];
      *(bf16x8*)&Wh[srow][skh]     = a0;
      *(bf16x8*)&Wh[srow][skh + 8] = a1;
      *(bf16x8*)&Wl[srow][skh]     = b0;
      *(bf16x8*)&Wl[srow][skh + 8] = b1;
    }
    __syncthreads();

    bf16x8 ah[4], al[4], bh[4], bl[4];
    #pragma unroll
    for (int mf = 0; mf < 4; mf++) {
      ah[mf] = *(const bf16x8*)&Xh[wm*64 + mf*16 + lo4][hi2*8];
      al[mf] = *(const bf16x8*)&Xl[wm*64 + mf*16 + lo4][hi2*8];
    }
    #pragma unroll
    for (int nf = 0; nf < 4; nf++) {
      bh[nf] = *(const bf16x8*)&Wh[wn*64 + nf*16 + lo4][hi2*8];
      bl[nf] = *(const bf16x8*)&Wl[wn*64 + nf*16 + lo4][hi2*8];
    }
    #pragma unroll
    for (int mf = 0; mf < 4; mf++)
      #pragma unroll
      for (int nf = 0; nf < 4; nf++) {
        acc[mf][nf] = __builtin_amdgcn_mfma_f32_16x16x32_bf16(ah[mf], bh[nf], acc[mf][nf], 0, 0, 0);
        acc[mf][nf] = __builtin_amdgcn_mfma_f32_16x16x32_bf16(ah[mf], bl[nf], acc[mf][nf], 0, 0, 0);
        acc[mf][nf] = __builtin_amdgcn_mfma_f32_16x16x32_bf16(al[mf], bh[nf], acc[mf][nf], 0, 0, 0);
      }
    __syncthreads();
  }

  // ---- epilogue ----
  const int mb = mt * 128 + wm * 64;
  const int nb = nt * 128 + wn * 64;
  #pragma unroll
  for (int mf = 0; mf < 4; mf++)
    #pragma unroll
    for (int nf = 0; nf < 4; nf++)
      #pragma unroll
      for (int i = 0; i < 4; i++) {
        int m = mb + mf*16 + hi2*4 + i;
        int n = nb + nf*16 + lo4;
        float val = acc[mf][nf][i];
        if (w == 0) {
          unsigned short h  = bft(val);
          unsigned short lo = bft(val - bf2f(h));
          size_t base = (size_t)(m >> 5) * 32768 + (size_t)(m & 31) * 512 + n;
          qpack[base]         = h;
          qpack[base + 16384] = lo;
        } else if (w == 1) {
          unsigned short h  = bft(val);
          unsigned short lo = bft(val - bf2f(h));
          khi[(size_t)m * 512 + n] = h;
          klo[(size_t)m * 512 + n] = lo;
        } else {
          int bb = m >> 11, t = m & 2047;
          vt[(size_t)bb * (512 * 2048) + (size_t)n * 2048 + t] = bft(val);
        }
      }
}

// ---------------------------------------------------------------------------
// Flash attention on MFMA. 512 threads = 8 waves; 32 q-rows/block (grid 512 ->
// 2 blocks/CU -> 4 waves/SIMD); 128-key tiles. Wave (qw,kw): qw=wave>>2 picks
// 16 q-rows, kw=wave&3 picks 32 keys (QK) / 128-d chunk (PV). 3-pass split
// QK^T with 2-deep register double-buffered fragments; P through XOR-swizzled
// LDS; cross-wave softmax stats in LDS. Q read from d_out (packed), O written
// over it in the epilogue (block-local aliasing).
// ---------------------------------------------------------------------------
__global__ __launch_bounds__(512, 4) void flash_mfma(
    const unsigned short* __restrict__ khi,
    const unsigned short* __restrict__ klo,
    const unsigned short* __restrict__ vt,
    const int* __restrict__ maskg,
    float* dout)                          // aliases Q storage - no restrict
{
  const int b  = blockIdx.x & 7;          // batch pinned to XCD
  const int qt = blockIdx.x >> 3;         // 0..63
  const int q0 = qt * 32;

  const int tid  = threadIdx.x;
  const int wave = tid >> 6, l = tid & 63;
  const int qw = wave >> 2, kw = wave & 3;
  const int lo4 = l & 15, hi2 = l >> 4;

  __shared__ unsigned short P[32 * 128];  // 8KB, XOR-swizzled rows
  __shared__ float pmax[4][32], psum[4][32];

  const unsigned short* qpk = (const unsigned short*)dout
      + (size_t)(b * 64 + qt) * 32768 + (size_t)(qw * 16 + lo4) * 512;
  const unsigned short* kbh = khi + ((size_t)(b * SEQ) + kw * 32 + lo4) * 512;
  const unsigned short* kbl = klo + ((size_t)(b * SEQ) + kw * 32 + lo4) * 512;
  const unsigned short* vb  = vt + (size_t)b * (512 * 2048) + (size_t)(kw * 128 + lo4) * 2048;
  const int* mb = maskg + b * SEQ + kw * 32 + lo4;

  f32x4 o[8];
  #pragma unroll
  for (int dt = 0; dt < 8; dt++)
    #pragma unroll
    for (int i = 0; i < 4; i++) o[dt][i] = 0.f;

  float m_run[4], l_run[4];
  #pragma unroll
  for (int i = 0; i < 4; i++) { m_run[i] = -3.0e38f; l_run[i] = 0.f; }

  #pragma unroll 1
  for (int kt = 0; kt < SEQ / 128; kt++) {
    const int key0 = kt * 128;

    // prefetch mask early; latency hides under QK
    const int ms0 = mb[key0];
    const int ms1 = mb[key0 + 16];

    // ---------------- QK^T (3-pass split), 2-deep reg pipeline ----------
    f32x4 S[2];
    #pragma unroll
    for (int kf = 0; kf < 2; kf++)
      #pragma unroll
      for (int i = 0; i < 4; i++) S[kf][i] = 0.f;

    bf16x8 fqh[2], fql[2], fkh0[2], fkh1[2], fkl0[2], fkl1[2];

#define LD_FRAGS(B, ST) do {                                              \
      const int d0_ = (ST) * 32 + hi2 * 8;                                \
      fqh[B] = *(const bf16x8*)(qpk + d0_);                               \
      fql[B] = *(const bf16x8*)(qpk + 16384 + d0_);                       \
      const size_t ko_ = (size_t)key0 * 512 + d0_;                        \
      fkh0[B] = *(const bf16x8*)(kbh + ko_);                              \
      fkh1[B] = *(const bf16x8*)(kbh + ko_ + 8192);                       \
      fkl0[B] = *(const bf16x8*)(kbl + ko_);                              \
      fkl1[B] = *(const bf16x8*)(kbl + ko_ + 8192);                       \
    } while (0)

    LD_FRAGS(0, 0);
    #pragma unroll
    for (int st = 0; st < 16; st++) {
      const int cur = st & 1, nxt = cur ^ 1;
      if (st < 15) {
        if (nxt) LD_FRAGS(1, st + 1); else LD_FRAGS(0, st + 1);
      }
      S[0] = __builtin_amdgcn_mfma_f32_16x16x32_bf16(fqh[cur], fkh0[cur], S[0], 0, 0, 0);
      S[1] = __builtin_amdgcn_mfma_f32_16x16x32_bf16(fqh[cur], fkh1[cur], S[1], 0, 0, 0);
      S[0] = __builtin_amdgcn_mfma_f32_16x16x32_bf16(fqh[cur], fkl0[cur], S[0], 0, 0, 0);
      S[1] = __builtin_amdgcn_mfma_f32_16x16x32_bf16(fqh[cur], fkl1[cur], S[1], 0, 0, 0);
      S[0] = __builtin_amdgcn_mfma_f32_16x16x32_bf16(fql[cur], fkh0[cur], S[0], 0, 0, 0);
      S[1] = __builtin_amdgcn_mfma_f32_16x16x32_bf16(fql[cur], fkh1[cur], S[1], 0, 0, 0);
    }
#undef LD_FRAGS

    // ---------------- mask ----------------
    #pragma unroll
    for (int i = 0; i < 4; i++) {
      if (!ms0) S[0][i] = -1.0e9f;
      if (!ms1) S[1][i] = -1.0e9f;
    }

    // ---------------- online softmax (cross-wave) ----------------
    #pragma unroll
    for (int i = 0; i < 4; i++) {
      float mx = fmaxf(S[0][i], S[1][i]);
      #pragma unroll
      for (int off = 1; off < 16; off <<= 1)
        mx = fmaxf(mx, __shfl_xor(mx, off, 64));
      if (lo4 == 0) pmax[kw][qw*16 + hi2*4 + i] = mx;
    }
    __syncthreads();

    float mnew[4], scale[4];
    #pragma unroll
    for (int i = 0; i < 4; i++) {
      int row = qw*16 + hi2*4 + i;
      float pm = fmaxf(fmaxf(pmax[0][row], pmax[1][row]),
                       fmaxf(pmax[2][row], pmax[3][row]));
      float mn = fmaxf(m_run[i], pm);
      mnew[i]  = mn;
      scale[i] = __expf(m_run[i] - mn);
      m_run[i] = mn;
    }
    #pragma unroll
    for (int dt = 0; dt < 8; dt++)
      #pragma unroll
      for (int i = 0; i < 4; i++) o[dt][i] *= scale[i];

    #pragma unroll
    for (int i = 0; i < 4; i++) {
      float p0 = __expf(S[0][i] - mnew[i]);
      float p1 = __expf(S[1][i] - mnew[i]);
      int row  = qw*16 + hi2*4 + i;
      int swz  = (row & 7) << 4;
      int b0   = (row*256 + (kw*32 + lo4)*2) ^ swz;
      int b1   = (row*256 + (kw*32 + 16 + lo4)*2) ^ swz;
      *(unsigned short*)((char*)P + b0) = bft(p0);
      *(unsigned short*)((char*)P + b1) = bft(p1);
      float ps = p0 + p1;
      #pragma unroll
      for (int off = 1; off < 16; off <<= 1) ps += __shfl_xor(ps, off, 64);
      if (lo4 == 0) psum[kw][row] = ps;
    }
    __syncthreads();

    #pragma unroll
    for (int i = 0; i < 4; i++) {
      int row = qw*16 + hi2*4 + i;
      float s = psum[0][row] + psum[1][row] + psum[2][row] + psum[3][row];
      l_run[i] = l_run[i] * scale[i] + s;
    }

    // ---------------- PV: O += P * V (vf 2-deep pipeline) ----------------
    bf16x8 pa[4];
    #pragma unroll
    for (int ks = 0; ks < 4; ks++) {
      int row  = qw*16 + lo4;
      int byte = (row*256 + (ks*32 + hi2*8)*2) ^ ((row & 7) << 4);
      pa[ks] = *(const bf16x8*)((const char*)P + byte);
    }

    const unsigned short* vk = vb + key0;
    bf16x8 vf[2];
    vf[0] = *(const bf16x8*)(vk + hi2*8);
    #pragma unroll
    for (int idx = 0; idx < 32; idx++) {
      const int cur = idx & 1, nxt = cur ^ 1;
      if (idx < 31) {
        const int ks_n = (idx + 1) >> 3, dt_n = (idx + 1) & 7;
        vf[nxt] = *(const bf16x8*)(vk + ks_n*32 + hi2*8 + (size_t)dt_n*16*2048);
      }
      const int ks = idx >> 3, dt = idx & 7;
      o[dt] = __builtin_amdgcn_mfma_f32_16x16x32_bf16(pa[ks], vf[cur], o[dt], 0, 0, 0);
    }
    __syncthreads();   // protect P/stats from next tile's writes
  }

  // ---------------- epilogue ----------------
  #pragma unroll
  for (int i = 0; i < 4; i++) {
    float inv  = 1.0f / l_run[i];
    int   rowg = b * SEQ + q0 + qw*16 + hi2*4 + i;
    #pragma unroll
    for (int dt = 0; dt < 8; dt++)
      dout[(size_t)rowg * 512 + kw*128 + dt*16 + lo4] = o[dt][i] * inv;
  }
}

extern "C" void kernel_launch(void* const* d_in, const int* in_sizes, int n_in,
                              void* d_out, int out_size, void* d_ws, size_t ws_size,
                              hipStream_t stream)
{
  const float* x    = (const float*)d_in[0];
  const float* Wq   = (const float*)d_in[1];
  const float* Wk   = (const float*)d_in[2];
  const float* Wv   = (const float*)d_in[3];
  const int*   mask = (const int*)d_in[4];

  unsigned short* wsh = (unsigned short*)d_ws;
  unsigned short* KHI = wsh;                 //  8,388,608 halfs
  unsigned short* KLO = wsh +  8388608;      //  8,388,608
  unsigned short* VT  = wsh + 16777216;      //  8,388,608
  unsigned short* WHI = wsh + 25165824;      //  1,572,864
  unsigned short* WLO = wsh + 26738688;      //  1,572,864  -> 56.6 MB total

  wsplit<<<1536, 256, 0, stream>>>(Wq, Wk, Wv, WHI, WLO);

  dim3 pgrid(4, 128, 3);
  proj_mfma<<<pgrid, 256, 0, stream>>>(x, WHI, WLO, KHI, KLO, VT,
                                       (unsigned short*)d_out);

  flash_mfma<<<512, 512, 0, stream>>>(KHI, KLO, VT, mask, (float*)d_out);
}

// Round 4
// 629.249 us; speedup vs baseline: 1.8227x; 1.8227x over previous
//
#include <hip/hip_runtime.h>
#include <hip/hip_bf16.h>
#include <cstddef>
#include <cstdint>

#define BATCH 8
#define SEQ   2048
#define DEMB  1024
#define DQ    512

typedef __attribute__((ext_vector_type(8))) _Float16 f16x8;
typedef __attribute__((ext_vector_type(4))) float f32x4;

#define MFMA16(a, b, c) __builtin_amdgcn_mfma_f32_16x16x32_f16((a), (b), (c), 0, 0, 0)

#define GLDS16(gp, lp) __builtin_amdgcn_global_load_lds(                      \
    (const __attribute__((address_space(1))) void*)(gp),                      \
    (__attribute__((address_space(3))) void*)(lp), 16, 0, 0)

// ---------------------------------------------------------------------------
// Transpose W (fp32 [k][n]) -> WT (fp16 [n][k]) for all three weight mats.
// ---------------------------------------------------------------------------
__global__ __launch_bounds__(256) void wprep(
    const float* __restrict__ Wq, const float* __restrict__ Wk,
    const float* __restrict__ Wv, _Float16* __restrict__ wt)
{
  int qidx = blockIdx.x * 256 + threadIdx.x;     // 0 .. 3*1024*128-1
  int w   = qidx >> 17;
  int rem = qidx & 131071;
  int k   = rem >> 7;                            // 0..1023
  int n   = (rem & 127) * 4;                     // 0..508
  const float* W = (w == 0) ? Wq : (w == 1) ? Wk : Wv;
  float4 v = *(const float4*)&W[(size_t)k * DQ + n];
  _Float16* dst = wt + (size_t)w * (DQ * DEMB);
  dst[(size_t)(n + 0) * DEMB + k] = (_Float16)v.x;
  dst[(size_t)(n + 1) * DEMB + k] = (_Float16)v.y;
  dst[(size_t)(n + 2) * DEMB + k] = (_Float16)v.z;
  dst[(size_t)(n + 3) * DEMB + k] = (_Float16)v.w;
}

// ---------------------------------------------------------------------------
// Projection GEMM, single-pass fp16 MFMA. C[16384,512] = X[16384,1024]*W.
// BM=128, BN=128, BK=32, 256 threads = 4 waves of 64x64, 4x4 16x16x32 frags.
// Outputs: w=0 Q hi/lo fp16 packed into d_out (64-row groups: g*65536 + plane
// *32768 + row*512 + d); w=1 K fp16 [t][d]; w=2 V fp16 transposed [b][d][t].
// ---------------------------------------------------------------------------
__global__ __launch_bounds__(256) void proj_f16(
    const float* __restrict__ x, const _Float16* __restrict__ wt,
    _Float16* __restrict__ kf, _Float16* __restrict__ vt,
    _Float16* __restrict__ qpack)
{
  const int w  = blockIdx.z;
  const int mt = blockIdx.y, nt = blockIdx.x;

  __shared__ _Float16 Xs[128][40];   // [m][k], pad to 40
  __shared__ _Float16 Ws[128][40];   // [n][k], pad to 40

  const int tid  = threadIdx.x;
  const int wave = tid >> 6, l = tid & 63;
  const int wm = wave >> 1, wn = wave & 1;
  const int lo4 = l & 15, hi2 = l >> 4;

  f32x4 acc[4][4];
  #pragma unroll
  for (int mf = 0; mf < 4; mf++)
    #pragma unroll
    for (int nf = 0; nf < 4; nf++)
      #pragma unroll
      for (int i = 0; i < 4; i++) acc[mf][nf][i] = 0.f;

  const int    srow  = tid >> 1;
  const int    skh   = (tid & 1) * 16;
  const size_t xbase = (size_t)(mt * 128 + srow) * DEMB + skh;
  const size_t wbase = (size_t)w * (DQ * DEMB) + (size_t)(nt * 128 + srow) * DEMB + skh;

  #pragma unroll 1
  for (int k0 = 0; k0 < DEMB; k0 += 32) {
    // stage X tile, converting fp32 -> fp16 in-register
    #pragma unroll
    for (int i = 0; i < 2; i++) {
      float4 t0 = *(const float4*)&x[xbase + k0 + i * 8];
      float4 t1 = *(const float4*)&x[xbase + k0 + i * 8 + 4];
      f16x8 hv;
      hv[0] = (_Float16)t0.x; hv[1] = (_Float16)t0.y;
      hv[2] = (_Float16)t0.z; hv[3] = (_Float16)t0.w;
      hv[4] = (_Float16)t1.x; hv[5] = (_Float16)t1.y;
      hv[6] = (_Float16)t1.z; hv[7] = (_Float16)t1.w;
      *(f16x8*)&Xs[srow][skh + i * 8] = hv;
    }
    // stage W tile (already fp16 [n][k])
    *(f16x8*)&Ws[srow][skh]     = *(const f16x8*)&wt[wbase + k0];
    *(f16x8*)&Ws[srow][skh + 8] = *(const f16x8*)&wt[wbase + k0 + 8];
    __syncthreads();

    f16x8 a[4], bfr[4];
    #pragma unroll
    for (int mf = 0; mf < 4; mf++)
      a[mf] = *(const f16x8*)&Xs[wm*64 + mf*16 + lo4][hi2*8];
    #pragma unroll
    for (int nf = 0; nf < 4; nf++)
      bfr[nf] = *(const f16x8*)&Ws[wn*64 + nf*16 + lo4][hi2*8];
    #pragma unroll
    for (int mf = 0; mf < 4; mf++)
      #pragma unroll
      for (int nf = 0; nf < 4; nf++)
        acc[mf][nf] = MFMA16(a[mf], bfr[nf], acc[mf][nf]);
    __syncthreads();
  }

  const int mb = mt * 128 + wm * 64;
  const int nb = nt * 128 + wn * 64;
  #pragma unroll
  for (int mf = 0; mf < 4; mf++)
    #pragma unroll
    for (int nf = 0; nf < 4; nf++)
      #pragma unroll
      for (int i = 0; i < 4; i++) {
        int m = mb + mf*16 + hi2*4 + i;
        int n = nb + nf*16 + lo4;
        float val = acc[mf][nf][i];
        if (w == 0) {
          _Float16 h  = (_Float16)val;
          _Float16 lo = (_Float16)(val - (float)h);
          size_t base = (size_t)(m >> 6) * 65536 + (size_t)(m & 63) * 512 + n;
          qpack[base]         = h;
          qpack[base + 32768] = lo;
        } else if (w == 1) {
          kf[(size_t)m * 512 + n] = (_Float16)val;
        } else {
          vt[(size_t)(m >> 11) * (512 * 2048) + (size_t)n * 2048 + (m & 2047)]
              = (_Float16)val;
        }
      }
}

// ---------------------------------------------------------------------------
// Flash attention, fp16, 2-pass split QK (qh*k + ql*k), K staged through LDS
// half-tiles (T3 2-phase, source-pre-swizzled for conflict-free ds_read_b128),
// V/Q from L2, P via XOR-swizzled LDS, cross-wave softmax stats in LDS.
// 512 threads = 8 waves; 64 q-rows/block; 128-key tiles; grid 256 (batch
// pinned to XCD). Q read from d_out (packed); O overwrites it in epilogue.
// ---------------------------------------------------------------------------
__global__ __launch_bounds__(512) void flash_f16(
    const _Float16* __restrict__ kfp, const _Float16* __restrict__ vtp,
    const int* __restrict__ maskg,
    float* dout)                          // aliases Q storage - no restrict
{
  const int bb = blockIdx.x & 7;          // batch -> XCD pin
  const int qt = blockIdx.x >> 3;         // 0..31
  const int q0 = qt * 64;

  const int tid  = threadIdx.x;
  const int wave = tid >> 6, l = tid & 63;
  const int qw = wave >> 2, kw = wave & 3;
  const int lo4 = l & 15, hi2 = l >> 4;

  __shared__ _Float16 Ks[2][128][256];    // 128 KB, src-swizzled
  __shared__ _Float16 P[64 * 128];        // 16 KB, XOR-swizzled rows
  __shared__ float pmax[4][64], psum[4][64];

  const _Float16* qpk   = (const _Float16*)dout + (size_t)(bb * 32 + qt) * 65536;
  const _Float16* kbase = kfp + (size_t)bb * SEQ * 512;
  const _Float16* vb    = vtp + (size_t)bb * (512 * 2048) + (size_t)(kw*128 + lo4) * 2048;
  const int*      mb    = maskg + bb * SEQ + kw * 32 + lo4;

  const _Float16* qrow0 = qpk + (size_t)(qw*32 + lo4) * 512;        // qf=0
  const _Float16* qrow1 = qpk + (size_t)(qw*32 + 16 + lo4) * 512;   // qf=1

  // stage K half H of tile KT into Ks[H] (buffer parity == half index).
  // LDS dest linear (lane-ordered); swizzle applied on the SOURCE d-offset
  // so the swizzled ds_read below recovers K[key][d] (rule: both sides).
#define STAGE_K(KT, H) do {                                                   \
    if ((KT) < 16) {                                                          \
      const int key0_ = (KT) * 128;                                           \
      char* lb_ = (char*)&Ks[(H)][0][0];                                      \
      _Pragma("unroll")                                                       \
      for (int r_ = 0; r_ < 8; r_++) {                                        \
        int key_ = r_*16 + (tid >> 5);                                        \
        int src_ = ((tid & 31) * 16) ^ ((key_ & 7) << 4);                     \
        const _Float16* g_ = kbase + (size_t)(key0_ + key_) * 512             \
                             + (H) * 256 + (src_ >> 1);                       \
        GLDS16(g_, lb_ + r_*8192 + tid*16);                                   \
      }                                                                       \
    }                                                                         \
  } while (0)

  f32x4 o[2][8];
  #pragma unroll
  for (int qf = 0; qf < 2; qf++)
    #pragma unroll
    for (int dt = 0; dt < 8; dt++)
      #pragma unroll
      for (int i = 0; i < 4; i++) o[qf][dt][i] = 0.f;

  float m_run[2][4], l_run[2][4];
  #pragma unroll
  for (int qf = 0; qf < 2; qf++)
    #pragma unroll
    for (int i = 0; i < 4; i++) { m_run[qf][i] = -3.0e38f; l_run[qf][i] = 0.f; }

  // prologue: stage kt0 half0
  STAGE_K(0, 0);
  __syncthreads();   // full drain (vmcnt 0) + barrier

  #pragma unroll 1
  for (int kt = 0; kt < 16; kt++) {
    const int key0 = kt * 128;
    const int ms0 = mb[key0];
    const int ms1 = mb[key0 + 16];

    f32x4 S[2][2];
    #pragma unroll
    for (int qf = 0; qf < 2; qf++)
      #pragma unroll
      for (int kfi = 0; kfi < 2; kfi++)
        #pragma unroll
        for (int i = 0; i < 4; i++) S[qf][kfi][i] = 0.f;

    const int swzk = (lo4 & 7) << 4;      // (key&7)<<4, same for both kf

#define QK_HALF(H) do {                                                       \
      const char* kl_ = (const char*)&Ks[(H)][0][0];                          \
      _Pragma("unroll")                                                       \
      for (int s_ = 0; s_ < 8; s_++) {                                        \
        const int st_ = (H)*8 + s_;                                           \
        const int d0_ = st_*32 + hi2*8;                                       \
        f16x8 qh0 = *(const f16x8*)(qrow0 + d0_);                             \
        f16x8 qh1 = *(const f16x8*)(qrow1 + d0_);                             \
        f16x8 ql0 = *(const f16x8*)(qrow0 + 32768 + d0_);                     \
        f16x8 ql1 = *(const f16x8*)(qrow1 + 32768 + d0_);                     \
        const int dby_ = (s_*64 + hi2*16) ^ swzk;                             \
        f16x8 k0 = *(const f16x8*)(kl_ + (kw*32 + lo4)*512 + dby_);           \
        f16x8 k1 = *(const f16x8*)(kl_ + (kw*32 + 16 + lo4)*512 + dby_);      \
        __builtin_amdgcn_s_setprio(1);                                        \
        S[0][0] = MFMA16(qh0, k0, S[0][0]);                                   \
        S[0][1] = MFMA16(qh0, k1, S[0][1]);                                   \
        S[1][0] = MFMA16(qh1, k0, S[1][0]);                                   \
        S[1][1] = MFMA16(qh1, k1, S[1][1]);                                   \
        S[0][0] = MFMA16(ql0, k0, S[0][0]);                                   \
        S[0][1] = MFMA16(ql0, k1, S[0][1]);                                   \
        S[1][0] = MFMA16(ql1, k0, S[1][0]);                                   \
        S[1][1] = MFMA16(ql1, k1, S[1][1]);                                   \
        __builtin_amdgcn_s_setprio(0);                                        \
      }                                                                       \
    } while (0)

    // phase A: stage half1 while computing half0
    STAGE_K(kt, 1);
    QK_HALF(0);
    __syncthreads();                      // drains stage(h1), publishes Ks[1]
    // phase B: compute half1
    QK_HALF(1);
#undef QK_HALF

    // ---------------- mask + row-max ----------------
    #pragma unroll
    for (int qf = 0; qf < 2; qf++)
      #pragma unroll
      for (int i = 0; i < 4; i++) {
        if (!ms0) S[qf][0][i] = -1.0e9f;
        if (!ms1) S[qf][1][i] = -1.0e9f;
        float mx = fmaxf(S[qf][0][i], S[qf][1][i]);
        #pragma unroll
        for (int off = 1; off < 16; off <<= 1)
          mx = fmaxf(mx, __shfl_xor(mx, off, 64));
        if (lo4 == 0) pmax[kw][qw*32 + qf*16 + hi2*4 + i] = mx;
      }
    __syncthreads();

    float mnew[2][4], scale[2][4];
    #pragma unroll
    for (int qf = 0; qf < 2; qf++)
      #pragma unroll
      for (int i = 0; i < 4; i++) {
        int row = qw*32 + qf*16 + hi2*4 + i;
        float pm = fmaxf(fmaxf(pmax[0][row], pmax[1][row]),
                         fmaxf(pmax[2][row], pmax[3][row]));
        float mn = fmaxf(m_run[qf][i], pm);
        mnew[qf][i]  = mn;
        scale[qf][i] = __expf(m_run[qf][i] - mn);
        m_run[qf][i] = mn;
      }
    #pragma unroll
    for (int qf = 0; qf < 2; qf++)
      #pragma unroll
      for (int dt = 0; dt < 8; dt++)
        #pragma unroll
        for (int i = 0; i < 4; i++) o[qf][dt][i] *= scale[qf][i];

    #pragma unroll
    for (int qf = 0; qf < 2; qf++)
      #pragma unroll
      for (int i = 0; i < 4; i++) {
        float p0 = __expf(S[qf][0][i] - mnew[qf][i]);
        float p1 = __expf(S[qf][1][i] - mnew[qf][i]);
        int row  = qw*32 + qf*16 + hi2*4 + i;
        int swz  = (row & 7) << 4;
        int b0   = (row*256 + (kw*32 + lo4)*2) ^ swz;
        int b1   = (row*256 + (kw*32 + 16 + lo4)*2) ^ swz;
        *(_Float16*)((char*)P + b0) = (_Float16)p0;
        *(_Float16*)((char*)P + b1) = (_Float16)p1;
        float ps = p0 + p1;
        #pragma unroll
        for (int off = 1; off < 16; off <<= 1) ps += __shfl_xor(ps, off, 64);
        if (lo4 == 0) psum[kw][row] = ps;
      }
    __syncthreads();

    #pragma unroll
    for (int qf = 0; qf < 2; qf++)
      #pragma unroll
      for (int i = 0; i < 4; i++) {
        int row = qw*32 + qf*16 + hi2*4 + i;
        float s = psum[0][row] + psum[1][row] + psum[2][row] + psum[3][row];
        l_run[qf][i] = l_run[qf][i] * scale[qf][i] + s;
      }

    // ---------------- stage next tile's half0 + PV ----------------
    STAGE_K(kt + 1, 0);

    f16x8 pa[2][4];
    #pragma unroll
    for (int qf = 0; qf < 2; qf++)
      #pragma unroll
      for (int ks = 0; ks < 4; ks++) {
        int row  = qw*32 + qf*16 + lo4;
        int byte = (row*256 + (ks*32 + hi2*8)*2) ^ ((row & 7) << 4);
        pa[qf][ks] = *(const f16x8*)((const char*)P + byte);
      }
    const _Float16* vk = vb + key0;
    #pragma unroll
    for (int ks = 0; ks < 4; ks++) {
      #pragma unroll
      for (int dt = 0; dt < 8; dt++) {
        f16x8 vf = *(const f16x8*)(vk + ks*32 + hi2*8 + (size_t)dt*16*2048);
        __builtin_amdgcn_s_setprio(1);
        o[0][dt] = MFMA16(pa[0][ks], vf, o[0][dt]);
        o[1][dt] = MFMA16(pa[1][ks], vf, o[1][dt]);
        __builtin_amdgcn_s_setprio(0);
      }
    }
    __syncthreads();   // drains stage(next h0), protects P/stats, publishes Ks[0]
  }
#undef STAGE_K

  // ---------------- epilogue: normalize and store ----------------
  #pragma unroll
  for (int qf = 0; qf < 2; qf++)
    #pragma unroll
    for (int i = 0; i < 4; i++) {
      float inv  = 1.0f / l_run[qf][i];
      int   rowg = bb * SEQ + q0 + qw*32 + qf*16 + hi2*4 + i;
      #pragma unroll
      for (int dt = 0; dt < 8; dt++)
        dout[(size_t)rowg * 512 + kw*128 + dt*16 + lo4] = o[qf][dt][i] * inv;
    }
}

extern "C" void kernel_launch(void* const* d_in, const int* in_sizes, int n_in,
                              void* d_out, int out_size, void* d_ws, size_t ws_size,
                              hipStream_t stream)
{
  const float* x    = (const float*)d_in[0];
  const float* Wq   = (const float*)d_in[1];
  const float* Wk   = (const float*)d_in[2];
  const float* Wv   = (const float*)d_in[3];
  const int*   mask = (const int*)d_in[4];

  _Float16* wsh = (_Float16*)d_ws;
  _Float16* KF = wsh;                  //  8,388,608 halfs (K fp16 [b*t][d])
  _Float16* VT = wsh + 8388608;        //  8,388,608 halfs (V^T fp16 [b][d][t])
  _Float16* WT = wsh + 16777216;       //  1,572,864 halfs -> 36.7 MB total

  wprep<<<1536, 256, 0, stream>>>(Wq, Wk, Wv, WT);

  dim3 pgrid(4, 128, 3);
  proj_f16<<<pgrid, 256, 0, stream>>>(x, WT, KF, VT, (_Float16*)d_out);

  flash_f16<<<256, 512, 0, stream>>>(KF, VT, mask, (float*)d_out);
}

// Round 5
// 434.915 us; speedup vs baseline: 2.6371x; 1.4468x over previous
//
#include <hip/hip_runtime.h>
#include <hip/hip_bf16.h>
#include <cstddef>
#include <cstdint>

#define BATCH 8
#define SEQ   2048
#define DEMB  1024
#define DQ    512

typedef __attribute__((ext_vector_type(8))) _Float16 f16x8;
typedef __attribute__((ext_vector_type(4))) float f32x4;

#define MFMA16(a, b, c) __builtin_amdgcn_mfma_f32_16x16x32_f16((a), (b), (c), 0, 0, 0)

#define GLDS16(gp, lp) __builtin_amdgcn_global_load_lds(                      \
    (const __attribute__((address_space(1))) void*)(gp),                      \
    (__attribute__((address_space(3))) void*)(lp), 16, 0, 0)

// ---------------------------------------------------------------------------
// Transpose W (fp32 [k][n]) -> WT (fp16 [n][k]) for all three weight mats.
// ---------------------------------------------------------------------------
__global__ __launch_bounds__(256) void wprep(
    const float* __restrict__ Wq, const float* __restrict__ Wk,
    const float* __restrict__ Wv, _Float16* __restrict__ wt)
{
  int qidx = blockIdx.x * 256 + threadIdx.x;     // 0 .. 3*1024*128-1
  int w   = qidx >> 17;
  int rem = qidx & 131071;
  int k   = rem >> 7;                            // 0..1023
  int n   = (rem & 127) * 4;                     // 0..508
  const float* W = (w == 0) ? Wq : (w == 1) ? Wk : Wv;
  float4 v = *(const float4*)&W[(size_t)k * DQ + n];
  _Float16* dst = wt + (size_t)w * (DQ * DEMB);
  dst[(size_t)(n + 0) * DEMB + k] = (_Float16)v.x;
  dst[(size_t)(n + 1) * DEMB + k] = (_Float16)v.y;
  dst[(size_t)(n + 2) * DEMB + k] = (_Float16)v.z;
  dst[(size_t)(n + 3) * DEMB + k] = (_Float16)v.w;
}

// ---------------------------------------------------------------------------
// Projection GEMM, single-pass fp16 MFMA. C[16384,512] = X[16384,1024]*W.
// BM=128, BN=128, BK=32, 256 threads = 4 waves of 64x64, 4x4 16x16x32 frags.
// Outputs: w=0 Q hi/lo fp16 packed into d_out (64-row groups: g*65536 + plane
// *32768 + row*512 + d); w=1 K fp16 [t][d]; w=2 V fp16 transposed [b][d][t].
// ---------------------------------------------------------------------------
__global__ __launch_bounds__(256) void proj_f16(
    const float* __restrict__ x, const _Float16* __restrict__ wt,
    _Float16* __restrict__ kf, _Float16* __restrict__ vt,
    _Float16* __restrict__ qpack)
{
  const int w  = blockIdx.z;
  const int mt = blockIdx.y, nt = blockIdx.x;

  __shared__ _Float16 Xs[128][40];   // [m][k], pad to 40
  __shared__ _Float16 Ws[128][40];   // [n][k], pad to 40

  const int tid  = threadIdx.x;
  const int wave = tid >> 6, l = tid & 63;
  const int wm = wave >> 1, wn = wave & 1;
  const int lo4 = l & 15, hi2 = l >> 4;

  f32x4 acc[4][4];
  #pragma unroll
  for (int mf = 0; mf < 4; mf++)
    #pragma unroll
    for (int nf = 0; nf < 4; nf++)
      #pragma unroll
      for (int i = 0; i < 4; i++) acc[mf][nf][i] = 0.f;

  const int    srow  = tid >> 1;
  const int    skh   = (tid & 1) * 16;
  const size_t xbase = (size_t)(mt * 128 + srow) * DEMB + skh;
  const size_t wbase = (size_t)w * (DQ * DEMB) + (size_t)(nt * 128 + srow) * DEMB + skh;

  #pragma unroll 1
  for (int k0 = 0; k0 < DEMB; k0 += 32) {
    // stage X tile, converting fp32 -> fp16 in-register
    #pragma unroll
    for (int i = 0; i < 2; i++) {
      float4 t0 = *(const float4*)&x[xbase + k0 + i * 8];
      float4 t1 = *(const float4*)&x[xbase + k0 + i * 8 + 4];
      f16x8 hv;
      hv[0] = (_Float16)t0.x; hv[1] = (_Float16)t0.y;
      hv[2] = (_Float16)t0.z; hv[3] = (_Float16)t0.w;
      hv[4] = (_Float16)t1.x; hv[5] = (_Float16)t1.y;
      hv[6] = (_Float16)t1.z; hv[7] = (_Float16)t1.w;
      *(f16x8*)&Xs[srow][skh + i * 8] = hv;
    }
    // stage W tile (already fp16 [n][k])
    *(f16x8*)&Ws[srow][skh]     = *(const f16x8*)&wt[wbase + k0];
    *(f16x8*)&Ws[srow][skh + 8] = *(const f16x8*)&wt[wbase + k0 + 8];
    __syncthreads();

    f16x8 a[4], bfr[4];
    #pragma unroll
    for (int mf = 0; mf < 4; mf++)
      a[mf] = *(const f16x8*)&Xs[wm*64 + mf*16 + lo4][hi2*8];
    #pragma unroll
    for (int nf = 0; nf < 4; nf++)
      bfr[nf] = *(const f16x8*)&Ws[wn*64 + nf*16 + lo4][hi2*8];
    #pragma unroll
    for (int mf = 0; mf < 4; mf++)
      #pragma unroll
      for (int nf = 0; nf < 4; nf++)
        acc[mf][nf] = MFMA16(a[mf], bfr[nf], acc[mf][nf]);
    __syncthreads();
  }

  const int mb = mt * 128 + wm * 64;
  const int nb = nt * 128 + wn * 64;
  #pragma unroll
  for (int mf = 0; mf < 4; mf++)
    #pragma unroll
    for (int nf = 0; nf < 4; nf++)
      #pragma unroll
      for (int i = 0; i < 4; i++) {
        int m = mb + mf*16 + hi2*4 + i;
        int n = nb + nf*16 + lo4;
        float val = acc[mf][nf][i];
        if (w == 0) {
          _Float16 h  = (_Float16)val;
          _Float16 lo = (_Float16)(val - (float)h);
          size_t base = (size_t)(m >> 6) * 65536 + (size_t)(m & 63) * 512 + n;
          qpack[base]         = h;
          qpack[base + 32768] = lo;
        } else if (w == 1) {
          kf[(size_t)m * 512 + n] = (_Float16)val;
        } else {
          vt[(size_t)(m >> 11) * (512 * 2048) + (size_t)n * 2048 + (m & 2047)]
              = (_Float16)val;
        }
      }
}

// ---------------------------------------------------------------------------
// Flash attention v3. 512 threads = 8 waves; 64 q-rows/block; 64-key tiles.
// Wave roles: qw = w&3 -> 16 q-rows (QK rows, softmax rows, PV rows, o rows);
//             kw = w>>2 -> QK: 32-key half; softmax: stats slot; PV: d-interleave.
// Q-hi plane in REGISTERS (loaded once); Q-lo pass streams from global
// (issued at phase start, hides under hi MFMAs). K and V staged through LDS
// half-d double buffers via global_load_lds with source-side 16B XOR swizzle.
// P via swizzled LDS; cross-wave softmax stats in LDS. O overwrites Q packed
// storage in the epilogue (block-local aliasing, reads all done first).
// ---------------------------------------------------------------------------
__global__ __launch_bounds__(512) void flash_v3(
    const _Float16* __restrict__ kfp, const _Float16* __restrict__ vtp,
    const int* __restrict__ maskg,
    float* dout)                          // aliases Q storage - no restrict
{
  const int bb = blockIdx.x & 7;          // batch -> XCD pin
  const int qt = blockIdx.x >> 3;         // 0..31
  const int q0 = qt * 64;

  const int tid = threadIdx.x;
  const int w = tid >> 6, l = tid & 63;
  const int qw = w & 3;                   // 16-row group
  const int kw = w >> 2;                  // 0..1
  const int lo4 = l & 15, hi2 = l >> 4;

  __shared__ _Float16 Kst[2][64][256];    // 64KB [buf][key][d-half], swz rows
  __shared__ _Float16 Vst[2][256][64];    // 64KB [buf][dloc][key], swz rows
  __shared__ _Float16 P[64 * 64];         // 8KB  [row][key], swz rows
  __shared__ float pmax[2][64], psum[2][64];

  const _Float16* qpk = (const _Float16*)dout + (size_t)(bb * 32 + qt) * 65536;
  const char*     kb  = (const char*)(kfp + (size_t)bb * SEQ * 512);
  const char*     vtb = (const char*)(vtp + (size_t)bb * (512 * 2048));
  const int*      mb  = maskg + bb * SEQ + kw * 32 + lo4;

  const _Float16* qhi = qpk + (size_t)(qw * 16 + lo4) * 512;
  const _Float16* qlo = qhi + 32768;

  // ---- Q-hi plane into registers (64 VGPR), once ----
  f16x8 fq[16];
  #pragma unroll
  for (int st = 0; st < 16; st++)
    fq[st] = *(const f16x8*)(qhi + st * 32 + hi2 * 8);

  // stage K half H (256 d-halfs) of tile KT into Kst[B]; 32KB = 4 GLDS/thread.
  // dest linear; source byte-offset XOR'd 16B-granular so swizzled ds_read
  // recovers K[key][d] (both-sides rule, validated r4).
#define STAGE_K(KT, H, B) do {                                                \
    if ((KT) < 32) {                                                          \
      const char* kg_ = kb + (size_t)(KT) * 64 * 1024;                        \
      char* lb_ = (char*)&Kst[(B)][0][0];                                     \
      _Pragma("unroll")                                                       \
      for (int i_ = 0; i_ < 4; i_++) {                                        \
        int D_ = i_ * 8192 + tid * 16;                                        \
        int row_ = D_ >> 9, cb_ = D_ & 511;                                   \
        GLDS16(kg_ + (size_t)row_ * 1024 + (H) * 512 +                        \
                   (cb_ ^ ((row_ & 7) << 4)),                                 \
               lb_ + D_);                                                     \
      }                                                                       \
    } } while (0)

  // stage V half H (256 d rows x 64 keys) of tile KT into Vst[B]
#define STAGE_V(KT, H, B) do {                                                \
    if ((KT) < 32) {                                                          \
      const char* vg_ = vtb + (size_t)(KT) * 128;                             \
      char* lb_ = (char*)&Vst[(B)][0][0];                                     \
      _Pragma("unroll")                                                       \
      for (int i_ = 0; i_ < 4; i_++) {                                        \
        int D_ = i_ * 8192 + tid * 16;                                        \
        int row_ = D_ >> 7, cb_ = D_ & 127;                                   \
        GLDS16(vg_ + (size_t)((H) * 256 + row_) * 4096 +                      \
                   (cb_ ^ ((row_ & 7) << 4)),                                 \
               lb_ + D_);                                                     \
      }                                                                       \
    } } while (0)

  // QK on half H from Kst[B]: Q-lo prefetched from global, hi from regs.
#define QK_HALF(H, B) do {                                                    \
    f16x8 ql_[8];                                                             \
    _Pragma("unroll")                                                         \
    for (int s_ = 0; s_ < 8; s_++)                                            \
      ql_[s_] = *(const f16x8*)(qlo + (H) * 256 + s_ * 32 + hi2 * 8);         \
    const char* kl_ = (const char*)&Kst[(B)][0][0];                           \
    const int r0_ = kw * 32 + lo4, r1_ = r0_ + 16;                            \
    const int sw_ = (lo4 & 7) << 4;                                           \
    _Pragma("unroll")                                                         \
    for (int s_ = 0; s_ < 8; s_++) {                                          \
      const int dby_ = (s_ * 32 + hi2 * 8) * 2;                               \
      f16x8 k0 = *(const f16x8*)(kl_ + r0_ * 512 + (dby_ ^ sw_));             \
      f16x8 k1 = *(const f16x8*)(kl_ + r1_ * 512 + (dby_ ^ sw_));             \
      __builtin_amdgcn_s_setprio(1);                                          \
      S[0] = MFMA16(fq[(H) * 8 + s_], k0, S[0]);                              \
      S[1] = MFMA16(fq[(H) * 8 + s_], k1, S[1]);                              \
      S[0] = MFMA16(ql_[s_], k0, S[0]);                                       \
      S[1] = MFMA16(ql_[s_], k1, S[1]);                                       \
      __builtin_amdgcn_s_setprio(0);                                          \
    } } while (0)

  // PV on d-half H from Vst[B]: o frags d = H*256 + j*32 + kw*16 + [0,16)
#define PV_HALF(H, B) do {                                                    \
    const char* vl_ = (const char*)&Vst[(B)][0][0];                           \
    _Pragma("unroll")                                                         \
    for (int j_ = 0; j_ < 8; j_++) {                                          \
      const int dl_ = j_ * 32 + kw * 16 + lo4;                                \
      const int vs_ = (dl_ & 7) << 4;                                         \
      f16x8 v0 = *(const f16x8*)(vl_ + dl_ * 128 + ((hi2 * 16) ^ vs_));       \
      f16x8 v1 = *(const f16x8*)(vl_ + dl_ * 128 + ((64 + hi2 * 16) ^ vs_));  \
      __builtin_amdgcn_s_setprio(1);                                          \
      o[(H) * 8 + j_] = MFMA16(pa[0], v0, o[(H) * 8 + j_]);                   \
      o[(H) * 8 + j_] = MFMA16(pa[1], v1, o[(H) * 8 + j_]);                   \
      __builtin_amdgcn_s_setprio(0);                                          \
    } } while (0)

  f32x4 o[16];
  #pragma unroll
  for (int f = 0; f < 16; f++)
    #pragma unroll
    for (int i = 0; i < 4; i++) o[f][i] = 0.f;

  float m_run[4], l_run[4];
  #pragma unroll
  for (int i = 0; i < 4; i++) { m_run[i] = -3.0e38f; l_run[i] = 0.f; }

  // prologue
  STAGE_K(0, 0, 0);
  __syncthreads();

  #pragma unroll 1
  for (int kt = 0; kt < 32; kt++) {
    const int key0 = kt * 64;
    const int ms0 = mb[key0];
    const int ms1 = mb[key0 + 16];

    f32x4 S[2];
    #pragma unroll
    for (int f = 0; f < 2; f++)
      #pragma unroll
      for (int i = 0; i < 4; i++) S[f][i] = 0.f;

    // ---- QK phase A: compute d-half 0, stage d-half 1 ----
    STAGE_K(kt, 1, 1);
    QK_HALF(0, 0);
    __syncthreads();
    // ---- QK phase B: compute d-half 1, stage next K h0 + this V h0 ----
    STAGE_K(kt + 1, 0, 0);
    STAGE_V(kt, 0, 0);
    QK_HALF(1, 1);
    __syncthreads();

    // ---- softmax 1: mask + row-max -> pmax ----
    #pragma unroll
    for (int i = 0; i < 4; i++) {
      if (!ms0) S[0][i] = -1.0e9f;
      if (!ms1) S[1][i] = -1.0e9f;
      float mx = fmaxf(S[0][i], S[1][i]);
      #pragma unroll
      for (int off = 1; off < 16; off <<= 1)
        mx = fmaxf(mx, __shfl_xor(mx, off, 64));
      if (lo4 == 0) pmax[kw][qw*16 + hi2*4 + i] = mx;
    }
    __syncthreads();

    // ---- softmax 2: scales, o-rescale, P write, psum ----
    float mnew[4], scale[4];
    #pragma unroll
    for (int i = 0; i < 4; i++) {
      int row = qw*16 + hi2*4 + i;
      float pm = fmaxf(pmax[0][row], pmax[1][row]);
      float mn = fmaxf(m_run[i], pm);
      mnew[i]  = mn;
      scale[i] = __expf(m_run[i] - mn);
      m_run[i] = mn;
    }
    #pragma unroll
    for (int f = 0; f < 16; f++)
      #pragma unroll
      for (int i = 0; i < 4; i++) o[f][i] *= scale[i];

    #pragma unroll
    for (int i = 0; i < 4; i++) {
      float p0 = __expf(S[0][i] - mnew[i]);
      float p1 = __expf(S[1][i] - mnew[i]);
      int row = qw*16 + hi2*4 + i;
      int swz = (row & 7) << 4;
      int b0  = (row*128 + (kw*32 + lo4)*2) ^ swz;
      int b1  = (row*128 + (kw*32 + 16 + lo4)*2) ^ swz;
      *(_Float16*)((char*)P + b0) = (_Float16)p0;
      *(_Float16*)((char*)P + b1) = (_Float16)p1;
      float ps = p0 + p1;
      #pragma unroll
      for (int off = 1; off < 16; off <<= 1) ps += __shfl_xor(ps, off, 64);
      if (lo4 == 0) psum[kw][row] = ps;
    }
    __syncthreads();

    #pragma unroll
    for (int i = 0; i < 4; i++) {
      int row = qw*16 + hi2*4 + i;
      l_run[i] = l_run[i] * scale[i] + psum[0][row] + psum[1][row];
    }

    // ---- PV: pa frags, d-half 0 (stage V h1), then d-half 1 ----
    f16x8 pa[2];
    {
      const int prow = qw*16 + lo4;
      const int psw  = (prow & 7) << 4;
      pa[0] = *(const f16x8*)((const char*)P + prow*128 + ((hi2*16) ^ psw));
      pa[1] = *(const f16x8*)((const char*)P + prow*128 + ((64 + hi2*16) ^ psw));
    }
    STAGE_V(kt, 1, 1);
    PV_HALF(0, 0);
    __syncthreads();
    PV_HALF(1, 1);
    // no barrier: next writes to Vst[1]/P are >=2 barriers away
  }
#undef STAGE_K
#undef STAGE_V
#undef QK_HALF
#undef PV_HALF

  // ---- epilogue: normalize and store (overwrites block's own Q region) ----
  #pragma unroll
  for (int i = 0; i < 4; i++) {
    float inv = 1.0f / l_run[i];
    int rowg = bb * SEQ + q0 + qw*16 + hi2*4 + i;
    #pragma unroll
    for (int h = 0; h < 2; h++)
      #pragma unroll
      for (int j = 0; j < 8; j++) {
        int d = h*256 + j*32 + kw*16 + lo4;
        dout[(size_t)rowg * 512 + d] = o[h*8 + j][i] * inv;
      }
  }
}

extern "C" void kernel_launch(void* const* d_in, const int* in_sizes, int n_in,
                              void* d_out, int out_size, void* d_ws, size_t ws_size,
                              hipStream_t stream)
{
  const float* x    = (const float*)d_in[0];
  const float* Wq   = (const float*)d_in[1];
  const float* Wk   = (const float*)d_in[2];
  const float* Wv   = (const float*)d_in[3];
  const int*   mask = (const int*)d_in[4];

  _Float16* wsh = (_Float16*)d_ws;
  _Float16* KF = wsh;                  //  8,388,608 halfs (K fp16 [b*t][d])
  _Float16* VT = wsh + 8388608;        //  8,388,608 halfs (V^T fp16 [b][d][t])
  _Float16* WT = wsh + 16777216;       //  1,572,864 halfs -> 36.7 MB total

  wprep<<<1536, 256, 0, stream>>>(Wq, Wk, Wv, WT);

  dim3 pgrid(4, 128, 3);
  proj_f16<<<pgrid, 256, 0, stream>>>(x, WT, KF, VT, (_Float16*)d_out);

  flash_v3<<<256, 512, 0, stream>>>(KF, VT, mask, (float*)d_out);
}

// Round 6
// 383.864 us; speedup vs baseline: 2.9879x; 1.1330x over previous
//
#include <hip/hip_runtime.h>
#include <hip/hip_bf16.h>
#include <cstddef>
#include <cstdint>

#define BATCH 8
#define SEQ   2048
#define DEMB  1024
#define DQ    512

typedef __attribute__((ext_vector_type(8))) _Float16 f16x8;
typedef __attribute__((ext_vector_type(4))) float f32x4;

#define MFMA16(a, b, c) __builtin_amdgcn_mfma_f32_16x16x32_f16((a), (b), (c), 0, 0, 0)

#define GLDS16(gp, lp) __builtin_amdgcn_global_load_lds(                      \
    (const __attribute__((address_space(1))) void*)(gp),                      \
    (__attribute__((address_space(3))) void*)(lp), 16, 0, 0)

// counted-vmcnt barrier (T4): wait then barrier in ONE asm so no memory op
// can be scheduled between or across them.
#define VM_BAR(N)                                                             \
  asm volatile("s_waitcnt vmcnt(" #N ")\n\ts_barrier" ::: "memory")
#define VM_LGKM_BAR(N)                                                        \
  asm volatile("s_waitcnt vmcnt(" #N ") lgkmcnt(0)\n\ts_barrier" ::: "memory")

// ---------------------------------------------------------------------------
// Transpose W (fp32 [k][n]) -> WT (fp16 [n][k]) for all three weight mats.
// ---------------------------------------------------------------------------
__global__ __launch_bounds__(256) void wprep(
    const float* __restrict__ Wq, const float* __restrict__ Wk,
    const float* __restrict__ Wv, _Float16* __restrict__ wt)
{
  int qidx = blockIdx.x * 256 + threadIdx.x;     // 0 .. 3*1024*128-1
  int w   = qidx >> 17;
  int rem = qidx & 131071;
  int k   = rem >> 7;                            // 0..1023
  int n   = (rem & 127) * 4;                     // 0..508
  const float* W = (w == 0) ? Wq : (w == 1) ? Wk : Wv;
  float4 v = *(const float4*)&W[(size_t)k * DQ + n];
  _Float16* dst = wt + (size_t)w * (DQ * DEMB);
  dst[(size_t)(n + 0) * DEMB + k] = (_Float16)v.x;
  dst[(size_t)(n + 1) * DEMB + k] = (_Float16)v.y;
  dst[(size_t)(n + 2) * DEMB + k] = (_Float16)v.z;
  dst[(size_t)(n + 3) * DEMB + k] = (_Float16)v.w;
}

// ---------------------------------------------------------------------------
// Projection GEMM, single-pass fp16 MFMA (unchanged from r5).
// ---------------------------------------------------------------------------
__global__ __launch_bounds__(256) void proj_f16(
    const float* __restrict__ x, const _Float16* __restrict__ wt,
    _Float16* __restrict__ kf, _Float16* __restrict__ vt,
    _Float16* __restrict__ qpack)
{
  const int w  = blockIdx.z;
  const int mt = blockIdx.y, nt = blockIdx.x;

  __shared__ _Float16 Xs[128][40];
  __shared__ _Float16 Ws[128][40];

  const int tid  = threadIdx.x;
  const int wave = tid >> 6, l = tid & 63;
  const int wm = wave >> 1, wn = wave & 1;
  const int lo4 = l & 15, hi2 = l >> 4;

  f32x4 acc[4][4];
  #pragma unroll
  for (int mf = 0; mf < 4; mf++)
    #pragma unroll
    for (int nf = 0; nf < 4; nf++)
      #pragma unroll
      for (int i = 0; i < 4; i++) acc[mf][nf][i] = 0.f;

  const int    srow  = tid >> 1;
  const int    skh   = (tid & 1) * 16;
  const size_t xbase = (size_t)(mt * 128 + srow) * DEMB + skh;
  const size_t wbase = (size_t)w * (DQ * DEMB) + (size_t)(nt * 128 + srow) * DEMB + skh;

  #pragma unroll 1
  for (int k0 = 0; k0 < DEMB; k0 += 32) {
    #pragma unroll
    for (int i = 0; i < 2; i++) {
      float4 t0 = *(const float4*)&x[xbase + k0 + i * 8];
      float4 t1 = *(const float4*)&x[xbase + k0 + i * 8 + 4];
      f16x8 hv;
      hv[0] = (_Float16)t0.x; hv[1] = (_Float16)t0.y;
      hv[2] = (_Float16)t0.z; hv[3] = (_Float16)t0.w;
      hv[4] = (_Float16)t1.x; hv[5] = (_Float16)t1.y;
      hv[6] = (_Float16)t1.z; hv[7] = (_Float16)t1.w;
      *(f16x8*)&Xs[srow][skh + i * 8] = hv;
    }
    *(f16x8*)&Ws[srow][skh]     = *(const f16x8*)&wt[wbase + k0];
    *(f16x8*)&Ws[srow][skh + 8] = *(const f16x8*)&wt[wbase + k0 + 8];
    __syncthreads();

    f16x8 a[4], bfr[4];
    #pragma unroll
    for (int mf = 0; mf < 4; mf++)
      a[mf] = *(const f16x8*)&Xs[wm*64 + mf*16 + lo4][hi2*8];
    #pragma unroll
    for (int nf = 0; nf < 4; nf++)
      bfr[nf] = *(const f16x8*)&Ws[wn*64 + nf*16 + lo4][hi2*8];
    #pragma unroll
    for (int mf = 0; mf < 4; mf++)
      #pragma unroll
      for (int nf = 0; nf < 4; nf++)
        acc[mf][nf] = MFMA16(a[mf], bfr[nf], acc[mf][nf]);
    __syncthreads();
  }

  const int mb = mt * 128 + wm * 64;
  const int nb = nt * 128 + wn * 64;
  #pragma unroll
  for (int mf = 0; mf < 4; mf++)
    #pragma unroll
    for (int nf = 0; nf < 4; nf++)
      #pragma unroll
      for (int i = 0; i < 4; i++) {
        int m = mb + mf*16 + hi2*4 + i;
        int n = nb + nf*16 + lo4;
        float val = acc[mf][nf][i];
        if (w == 0) {
          _Float16 h  = (_Float16)val;
          _Float16 lo = (_Float16)(val - (float)h);
          size_t base = (size_t)(m >> 6) * 65536 + (size_t)(m & 63) * 512 + n;
          qpack[base]         = h;
          qpack[base + 32768] = lo;
        } else if (w == 1) {
          kf[(size_t)m * 512 + n] = (_Float16)val;
        } else {
          vt[(size_t)(m >> 11) * (512 * 2048) + (size_t)n * 2048 + (m & 2047)]
              = (_Float16)val;
        }
      }
}

// ---------------------------------------------------------------------------
// Flash attention v4: counted-vmcnt pipeline, merged single-exchange softmax,
// Q hi+lo fully in registers, mask in LDS -> the kt loop's only global
// traffic is global_load_lds (exact vmcnt accounting).
// 8 waves: qw=w&3 -> 16 q-rows; kw=w>>2 -> key-half (QK) / d-interleave (PV).
// Per kt, 4 raw barriers, stages always >=1 phase ahead of their consumer:
//  P1: issue K.h1, V.h0   | vmcnt(8)->Ks[0] | QK half0
//  P2: vmcnt(4)->Ks[1]    | QK half1 | issue V.h1, K'.h0 | local softmax
//  P3: vmcnt(8)+lgkm ->Vst[0],P,stats
//  P4: rescale o, scaled pa | PV half0 | vmcnt(4)->Vst[1] | PV half1
// ---------------------------------------------------------------------------
__global__ __launch_bounds__(512, 2) void flash_v4(
    const _Float16* __restrict__ kfp, const _Float16* __restrict__ vtp,
    const int* __restrict__ maskg,
    float* dout)                          // aliases Q storage - no restrict
{
  const int bb = blockIdx.x & 7;          // batch -> XCD pin
  const int qt = blockIdx.x >> 3;         // 0..31
  const int q0 = qt * 64;

  const int tid = threadIdx.x;
  const int w = tid >> 6, l = tid & 63;
  const int qw = w & 3;                   // 16-row group
  const int kw = w >> 2;                  // 0..1
  const int lo4 = l & 15, hi2 = l >> 4;

  __shared__ _Float16 Kst[2][64][256];    // 64KB, src-swizzled
  __shared__ _Float16 Vst[2][256][64];    // 64KB, src-swizzled
  __shared__ _Float16 P[64 * 64];         // 8KB, XOR-swizzled rows
  __shared__ int      Msk[2048];          // 8KB
  __shared__ float pmax[2][64], psum[2][64];

  const _Float16* qpk = (const _Float16*)dout + (size_t)(bb * 32 + qt) * 65536;
  const char*     kb  = (const char*)(kfp + (size_t)bb * SEQ * 512);
  const char*     vtb = (const char*)(vtp + (size_t)bb * (512 * 2048));

  const _Float16* qhi = qpk + (size_t)(qw * 16 + lo4) * 512;
  const _Float16* qlo = qhi + 32768;

#define STAGE_K(KT, H, B) do {                                                \
    const char* kg_ = kb + (size_t)(KT) * 64 * 1024;                          \
    char* lb_ = (char*)&Kst[(B)][0][0];                                       \
    _Pragma("unroll")                                                         \
    for (int i_ = 0; i_ < 4; i_++) {                                          \
      int D_ = i_ * 8192 + tid * 16;                                          \
      int row_ = D_ >> 9, cb_ = D_ & 511;                                     \
      GLDS16(kg_ + (size_t)row_ * 1024 + (H) * 512 +                          \
                 (cb_ ^ ((row_ & 7) << 4)),                                   \
             lb_ + D_);                                                       \
    } } while (0)

#define STAGE_V(KT, H, B) do {                                                \
    const char* vg_ = vtb + (size_t)(KT) * 128;                               \
    char* lb_ = (char*)&Vst[(B)][0][0];                                       \
    _Pragma("unroll")                                                         \
    for (int i_ = 0; i_ < 4; i_++) {                                          \
      int D_ = i_ * 8192 + tid * 16;                                          \
      int row_ = D_ >> 7, cb_ = D_ & 127;                                     \
      GLDS16(vg_ + (size_t)((H) * 256 + row_) * 4096 +                        \
                 (cb_ ^ ((row_ & 7) << 4)),                                   \
             lb_ + D_);                                                       \
    } } while (0)

#define QK_HALF(H, B) do {                                                    \
    const char* kl_ = (const char*)&Kst[(B)][0][0];                           \
    const int r0_ = kw * 32 + lo4, r1_ = r0_ + 16;                            \
    const int sw_ = (lo4 & 7) << 4;                                           \
    _Pragma("unroll")                                                         \
    for (int s_ = 0; s_ < 8; s_++) {                                          \
      const int dby_ = (s_ * 32 + hi2 * 8) * 2;                               \
      f16x8 k0 = *(const f16x8*)(kl_ + r0_ * 512 + (dby_ ^ sw_));             \
      f16x8 k1 = *(const f16x8*)(kl_ + r1_ * 512 + (dby_ ^ sw_));             \
      __builtin_amdgcn_s_setprio(1);                                          \
      S[0] = MFMA16(fq[(H) * 8 + s_], k0, S[0]);                              \
      S[1] = MFMA16(fq[(H) * 8 + s_], k1, S[1]);                              \
      S[0] = MFMA16(fql[(H) * 8 + s_], k0, S[0]);                             \
      S[1] = MFMA16(fql[(H) * 8 + s_], k1, S[1]);                             \
      __builtin_amdgcn_s_setprio(0);                                          \
    } } while (0)

#define PV_HALF(H, B) do {                                                    \
    const char* vl_ = (const char*)&Vst[(B)][0][0];                           \
    _Pragma("unroll")                                                         \
    for (int j_ = 0; j_ < 8; j_++) {                                          \
      const int dl_ = j_ * 32 + kw * 16 + lo4;                                \
      const int vs_ = (dl_ & 7) << 4;                                         \
      f16x8 v0 = *(const f16x8*)(vl_ + dl_ * 128 + ((hi2 * 16) ^ vs_));       \
      f16x8 v1 = *(const f16x8*)(vl_ + dl_ * 128 + ((64 + hi2 * 16) ^ vs_));  \
      __builtin_amdgcn_s_setprio(1);                                          \
      o[(H) * 8 + j_] = MFMA16(pa[0], v0, o[(H) * 8 + j_]);                   \
      o[(H) * 8 + j_] = MFMA16(pa[1], v1, o[(H) * 8 + j_]);                   \
      __builtin_amdgcn_s_setprio(0);                                          \
    } } while (0)

  // ---- prologue: mask -> LDS, Q hi+lo -> regs, stage kt0.h0, full drain ----
  {
    int4 mv = *(const int4*)&maskg[bb * SEQ + tid * 4];
    *(int4*)&Msk[tid * 4] = mv;
  }
  f16x8 fq[16], fql[16];
  #pragma unroll
  for (int st = 0; st < 16; st++) {
    fq[st]  = *(const f16x8*)(qhi + st * 32 + hi2 * 8);
    fql[st] = *(const f16x8*)(qlo + st * 32 + hi2 * 8);
  }
  STAGE_K(0, 0, 0);
  __syncthreads();

  f32x4 o[16];
  #pragma unroll
  for (int f = 0; f < 16; f++)
    #pragma unroll
    for (int i = 0; i < 4; i++) o[f][i] = 0.f;

  float m_run[4], l_run[4], m_runP = -3.0e38f;
  #pragma unroll
  for (int i = 0; i < 4; i++) { m_run[i] = -3.0e38f; l_run[i] = 0.f; }

  #pragma unroll 1
  for (int kt = 0; kt < 32; kt++) {
    const int key0 = kt * 64;

    // ---- P1: issue K.h1 + V.h0; publish Ks[0] (prev E drained); QK h0 ----
    STAGE_K(kt, 1, 1);                    // A
    STAGE_V(kt, 0, 0);                    // C
    VM_BAR(8);                            // drains E(prev) -> Ks[0] ready

    f32x4 S[2];
    #pragma unroll
    for (int f = 0; f < 2; f++)
      #pragma unroll
      for (int i = 0; i < 4; i++) S[f][i] = 0.f;
    QK_HALF(0, 0);

    // ---- P2: publish Ks[1]; QK h1; issue V.h1 + K'.h0; local softmax ----
    VM_BAR(4);                            // drains A -> Ks[1] ready
    const int ms0 = Msk[key0 + kw * 32 + lo4];
    const int ms1 = Msk[key0 + kw * 32 + 16 + lo4];
    QK_HALF(1, 1);

    STAGE_V(kt, 1, 1);                    // D
    STAGE_K(kt + 1, 0, 0);                // E (kt=31 reads past K into VT: benign)

    #pragma unroll
    for (int i = 0; i < 4; i++) {
      if (!ms0) S[0][i] = -1.0e9f;
      if (!ms1) S[1][i] = -1.0e9f;
      float mx = fmaxf(S[0][i], S[1][i]);
      #pragma unroll
      for (int off = 1; off < 16; off <<= 1)
        mx = fmaxf(mx, __shfl_xor(mx, off, 64));
      float p0 = __expf(S[0][i] - mx);
      float p1 = __expf(S[1][i] - mx);
      int row = qw*16 + hi2*4 + i;
      int swz = (row & 7) << 4;
      int b0  = (row*128 + (kw*32 + lo4)*2) ^ swz;
      int b1  = (row*128 + (kw*32 + 16 + lo4)*2) ^ swz;
      *(_Float16*)((char*)P + b0) = (_Float16)p0;
      *(_Float16*)((char*)P + b1) = (_Float16)p1;
      float ps = p0 + p1;
      #pragma unroll
      for (int off = 1; off < 16; off <<= 1) ps += __shfl_xor(ps, off, 64);
      if (lo4 == 0) { pmax[kw][row] = mx; psum[kw][row] = ps; }
    }

    // ---- P3: publish Vst[0] + P + stats ----
    VM_LGKM_BAR(8);                       // drains C -> Vst[0]; lgkm -> P/stats

    // ---- P4: merge stats, rescale o, scaled pa; PV h0; publish Vst[1]; PV h1
    float oscale[4];
    #pragma unroll
    for (int i = 0; i < 4; i++) {
      int row = qw*16 + hi2*4 + i;
      float m0 = pmax[0][row], m1 = pmax[1][row];
      float s0 = psum[0][row], s1 = psum[1][row];
      float mn = fmaxf(m_run[i], fmaxf(m0, m1));
      oscale[i] = __expf(m_run[i] - mn);
      l_run[i] = l_run[i] * oscale[i]
               + __expf(m0 - mn) * s0 + __expf(m1 - mn) * s1;
      m_run[i] = mn;
    }
    #pragma unroll
    for (int f = 0; f < 16; f++)
      #pragma unroll
      for (int i = 0; i < 4; i++) o[f][i] *= oscale[i];

    f16x8 pa[2];
    {
      const int prow = qw*16 + lo4;
      float m0p = pmax[0][prow], m1p = pmax[1][prow];
      float mnp = fmaxf(m_runP, fmaxf(m0p, m1p));
      m_runP = mnp;
      _Float16 c0 = (_Float16)__expf(m0p - mnp);
      _Float16 c1 = (_Float16)__expf(m1p - mnp);
      const int psw = (prow & 7) << 4;
      pa[0] = *(const f16x8*)((const char*)P + prow*128 + ((hi2*16) ^ psw));
      pa[1] = *(const f16x8*)((const char*)P + prow*128 + ((64 + hi2*16) ^ psw));
      pa[0] = pa[0] * c0;
      pa[1] = pa[1] * c1;
    }

    PV_HALF(0, 0);
    VM_BAR(4);                            // drains D -> Vst[1] ready (E stays)
    PV_HALF(1, 1);
  }
#undef STAGE_K
#undef STAGE_V
#undef QK_HALF
#undef PV_HALF

  asm volatile("s_waitcnt vmcnt(0)" ::: "memory");

  // ---- epilogue: normalize and store (overwrites block's own Q region) ----
  #pragma unroll
  for (int i = 0; i < 4; i++) {
    float inv = 1.0f / l_run[i];
    int rowg = bb * SEQ + q0 + qw*16 + hi2*4 + i;
    #pragma unroll
    for (int h = 0; h < 2; h++)
      #pragma unroll
      for (int j = 0; j < 8; j++) {
        int d = h*256 + j*32 + kw*16 + lo4;
        dout[(size_t)rowg * 512 + d] = o[h*8 + j][i] * inv;
      }
  }
}

extern "C" void kernel_launch(void* const* d_in, const int* in_sizes, int n_in,
                              void* d_out, int out_size, void* d_ws, size_t ws_size,
                              hipStream_t stream)
{
  const float* x    = (const float*)d_in[0];
  const float* Wq   = (const float*)d_in[1];
  const float* Wk   = (const float*)d_in[2];
  const float* Wv   = (const float*)d_in[3];
  const int*   mask = (const int*)d_in[4];

  _Float16* wsh = (_Float16*)d_ws;
  _Float16* KF = wsh;                  //  8,388,608 halfs (K fp16 [b*t][d])
  _Float16* VT = wsh + 8388608;        //  8,388,608 halfs (V^T fp16 [b][d][t])
  _Float16* WT = wsh + 16777216;       //  1,572,864 halfs -> 36.7 MB total

  wprep<<<1536, 256, 0, stream>>>(Wq, Wk, Wv, WT);

  dim3 pgrid(4, 128, 3);
  proj_f16<<<pgrid, 256, 0, stream>>>(x, WT, KF, VT, (_Float16*)d_out);

  flash_v4<<<256, 512, 0, stream>>>(KF, VT, mask, (float*)d_out);
}